// Round 1
// baseline (1931.865 us; speedup 1.0000x reference)
//
#include <hip/hip_runtime.h>
#include <math.h>

#define B_ 256
#define HID_ 512
#define H_ 8
#define D_ 64
#define FF_ 2048
#define L_ 6
#define EPS_ATTN 1e-6f
#define EPS_LN 1e-5f

typedef unsigned short u16;
typedef __attribute__((ext_vector_type(8))) short short8;
typedef __attribute__((ext_vector_type(4))) float floatx4;

__device__ inline u16 f2bf(float f) {
  union { float f; unsigned u; } un; un.f = f;
  unsigned u = un.u;
  u += 0x7FFFu + ((u >> 16) & 1u);   // RNE truncate to bf16
  return (u16)(u >> 16);
}

// ---------------- embedding + sinusoidal PE ----------------
__global__ __launch_bounds__(256) void embed_kernel(
    const int* __restrict__ x, const int* __restrict__ pos,
    const float* __restrict__ emb, float* __restrict__ h, u16* __restrict__ hb) {
  int b = blockIdx.x, t = threadIdx.x;
  int tok = x[b];
  float p = (float)pos[0];
  for (int i = t; i < HID_; i += 256) {
    int pair = i >> 1;
    float freq = powf(10000.f, -(float)pair * (1.f / 256.f));
    float ang = p * freq;
    float pe = (i & 1) ? cosf(ang) : sinf(ang);
    float v = emb[(size_t)tok * HID_ + i] + pe;
    h[b * HID_ + i] = v;
    hb[b * HID_ + i] = f2bf(v);
  }
}

// ---------------- bf16 MFMA GEMM: C[M,N] = act(A[M,K] @ W[K,N] + bias) ------
// A: bf16 row-major. W: fp32 row-major (converted+transposed into LDS).
// BM=64, BN=64, BK=32; 256 threads = 4 waves; wave w owns rows [w*16, w*16+16).
// act: 0 none, 1 elu+1, 2 relu
__device__ inline void gemm_body(const u16* __restrict__ A, const float* __restrict__ W,
                                 const float* __restrict__ bias,
                                 float* __restrict__ Cf, u16* __restrict__ Cb,
                                 int N, int K, int act, int m0, int n0) {
  __shared__ u16 sA[64][40];   // [m][k], row padded 32->40 bf16 (frag reads 2-way-free)
  __shared__ u16 sB[64][40];   // [n][k] transposed
  int t = threadIdx.x;
  int lane = t & 63, wv = t >> 6;
  floatx4 acc[4] = {};
  for (int k0 = 0; k0 < K; k0 += 32) {
    { // stage A: 64 rows x 32 bf16, 16B per thread
      int r = t >> 2, c = t & 3;
      *(float4*)(&sA[r][c * 8]) =
          *(const float4*)(A + (size_t)(m0 + r) * K + k0 + c * 8);
    }
    { // stage W with cvt + transpose: pack k-pairs into b32 writes
#pragma unroll
      for (int i = 0; i < 4; i++) {
        int pp = t + i * 256;           // 0..1023 pairs
        int n = pp & 63, r2 = pp >> 6;  // r2: 0..15
        int k = k0 + r2 * 2;
        float w0 = W[(size_t)k * N + n0 + n];
        float w1 = W[(size_t)(k + 1) * N + n0 + n];
        unsigned pk = (unsigned)f2bf(w0) | ((unsigned)f2bf(w1) << 16);
        *(unsigned*)(&sB[n][r2 * 2]) = pk;
      }
    }
    __syncthreads();
    short8 af = *(const short8*)(&sA[wv * 16 + (lane & 15)][(lane >> 4) * 8]);
#pragma unroll
    for (int nt = 0; nt < 4; nt++) {
      short8 bf = *(const short8*)(&sB[nt * 16 + (lane & 15)][(lane >> 4) * 8]);
      acc[nt] = __builtin_amdgcn_mfma_f32_16x16x32_bf16(af, bf, acc[nt], 0, 0, 0);
    }
    __syncthreads();
  }
#pragma unroll
  for (int nt = 0; nt < 4; nt++) {
#pragma unroll
    for (int r = 0; r < 4; r++) {
      int row = m0 + wv * 16 + (lane >> 4) * 4 + r;  // C/D: row=quad*4+reg
      int col = n0 + nt * 16 + (lane & 15);          //      col=lane&15
      float v = acc[nt][r] + bias[col];
      if (act == 1) v = v > 0.f ? v + 1.f : expf(v);  // elu(x)+1
      else if (act == 2) v = fmaxf(v, 0.f);
      if (Cf) Cf[(size_t)row * N + col] = v;
      if (Cb) Cb[(size_t)row * N + col] = f2bf(v);
    }
  }
}

__global__ __launch_bounds__(256) void gemm_f32out(const u16* __restrict__ A,
    const float* __restrict__ W, const float* __restrict__ bias,
    float* __restrict__ C, int N, int K, int act) {
  gemm_body(A, W, bias, C, nullptr, N, K, act, blockIdx.y * 64, blockIdx.x * 64);
}
__global__ __launch_bounds__(256) void gemm_bf16out(const u16* __restrict__ A,
    const float* __restrict__ W, const float* __restrict__ bias,
    u16* __restrict__ C, int N, int K, int act) {
  gemm_body(A, W, bias, nullptr, C, N, K, act, blockIdx.y * 64, blockIdx.x * 64);
}
// fused Q/K/V: grid.x = 24 (8 n-tiles x 3 matrices)
__global__ __launch_bounds__(256) void gemm_qkv(const u16* __restrict__ A,
    const float* __restrict__ Wq, const float* __restrict__ Wk, const float* __restrict__ Wv,
    const float* __restrict__ bq, const float* __restrict__ bk, const float* __restrict__ bv,
    float* __restrict__ qkv) {
  int sel = blockIdx.x >> 3;
  int n0 = (blockIdx.x & 7) * 64;
  const float* W = sel == 0 ? Wq : (sel == 1 ? Wk : Wv);
  const float* bias = sel == 0 ? bq : (sel == 1 ? bk : bv);
  float* C = qkv + (size_t)sel * B_ * HID_;
  gemm_body(A, W, bias, C, nullptr, HID_, HID_, sel < 2 ? 1 : 0, blockIdx.y * 64, n0);
}

// ---------------- linear-attention state update (the HBM-bound pass) -------
// block = (b*H + h); S_out = S + k (x) v; num = q . S_out; den = q . (Z+k)
__global__ __launch_bounds__(256) void state_kernel(
    const float* __restrict__ S_in, const float* __restrict__ Z_in,
    const float* __restrict__ qkv, float* __restrict__ S_out,
    float* __restrict__ Z_out, u16* __restrict__ attnb) {
  int bh = blockIdx.x;
  int b = bh >> 3, hh = bh & 7;
  const float* q = qkv + (size_t)b * HID_ + hh * D_;
  const float* k = q + (size_t)B_ * HID_;
  const float* v = q + (size_t)2 * B_ * HID_;
  __shared__ float qs[D_], ks[D_], vs[D_];
  __shared__ float part[16][D_];
  int t = threadIdx.x;
  if (t < D_) { qs[t] = q[t]; ks[t] = k[t]; vs[t] = v[t]; }
  __syncthreads();
  int tm = (t & 15) << 2;  // column base (float4)
  int rg = t >> 4;         // row group 0..15 (rows rg*4..rg*4+3)
  const float4* Sp = (const float4*)(S_in + (size_t)bh * D_ * D_);
  float4* So = (float4*)(S_out + (size_t)bh * D_ * D_);
  float4 vv = *(const float4*)(vs + tm);
  float4 acc = {0.f, 0.f, 0.f, 0.f};
#pragma unroll
  for (int i = 0; i < 4; i++) {
    int d = rg * 4 + i;
    float kd = ks[d], qd = qs[d];
    float4 s = Sp[(d * D_ + tm) >> 2];
    s.x += kd * vv.x; s.y += kd * vv.y; s.z += kd * vv.z; s.w += kd * vv.w;
    So[(d * D_ + tm) >> 2] = s;
    acc.x += qd * s.x; acc.y += qd * s.y; acc.z += qd * s.z; acc.w += qd * s.w;
  }
  *(float4*)(&part[rg][tm]) = acc;
  __syncthreads();
  if (t < D_) {
    float num = 0.f;
#pragma unroll
    for (int r = 0; r < 16; r++) num += part[r][t];
    float zk = Z_in[(size_t)bh * D_ + t] + ks[t];
    Z_out[(size_t)bh * D_ + t] = zk;
    float dv = qs[t] * zk;
#pragma unroll
    for (int off = 32; off > 0; off >>= 1) dv += __shfl_down(dv, off);
    float den = __shfl(dv, 0) + EPS_ATTN;
    attnb[(size_t)b * HID_ + hh * D_ + t] = f2bf(num / den);
  }
}

// ---------------- residual + LayerNorm (row per block) ----------------------
__global__ __launch_bounds__(256) void ln_kernel(
    const float* __restrict__ x, const float* __restrict__ res,
    const float* __restrict__ g, const float* __restrict__ bb,
    float* __restrict__ out_f, u16* __restrict__ out_b) {
  int b = blockIdx.x, t = threadIdx.x;
  float v0 = x[b * HID_ + t] + (res ? res[b * HID_ + t] : 0.f);
  float v1 = x[b * HID_ + 256 + t] + (res ? res[b * HID_ + 256 + t] : 0.f);
  float s = v0 + v1, ss = v0 * v0 + v1 * v1;
#pragma unroll
  for (int off = 32; off > 0; off >>= 1) {
    s += __shfl_down(s, off);
    ss += __shfl_down(ss, off);
  }
  __shared__ float rs[4], rss[4];
  int w = t >> 6;
  if ((t & 63) == 0) { rs[w] = s; rss[w] = ss; }
  __syncthreads();
  float S = rs[0] + rs[1] + rs[2] + rs[3];
  float SS = rss[0] + rss[1] + rss[2] + rss[3];
  float mean = S * (1.f / HID_);
  float var = SS * (1.f / HID_) - mean * mean;
  float inv = rsqrtf(var + EPS_LN);
  float o0 = (v0 - mean) * inv * g[t] + bb[t];
  float o1 = (v1 - mean) * inv * g[256 + t] + bb[256 + t];
  out_f[b * HID_ + t] = o0;
  out_f[b * HID_ + 256 + t] = o1;
  if (out_b) {
    out_b[b * HID_ + t] = f2bf(o0);
    out_b[b * HID_ + 256 + t] = f2bf(o1);
  }
}

extern "C" void kernel_launch(void* const* d_in, const int* in_sizes, int n_in,
                              void* d_out, int out_size, void* d_ws, size_t ws_size,
                              hipStream_t stream) {
  const int* x = (const int*)d_in[0];
  const int* pos = (const int*)d_in[1];
  const float* S = (const float*)d_in[2];
  const float* Z = (const float*)d_in[3];
  const float* emb = (const float*)d_in[4];
  const float* Wq = (const float*)d_in[5];
  const float* bq = (const float*)d_in[6];
  const float* Wk = (const float*)d_in[7];
  const float* bk = (const float*)d_in[8];
  const float* Wv = (const float*)d_in[9];
  const float* bv = (const float*)d_in[10];
  const float* Wo = (const float*)d_in[11];
  const float* bo = (const float*)d_in[12];
  const float* W1 = (const float*)d_in[13];
  const float* b1 = (const float*)d_in[14];
  const float* W2 = (const float*)d_in[15];
  const float* b2 = (const float*)d_in[16];
  const float* ln1_g = (const float*)d_in[17];
  const float* ln1_b = (const float*)d_in[18];
  const float* ln2_g = (const float*)d_in[19];
  const float* ln2_b = (const float*)d_in[20];
  const float* lnf_g = (const float*)d_in[21];
  const float* lnf_b = (const float*)d_in[22];

  float* out_h = (float*)d_out;
  float* out_S = out_h + (size_t)B_ * HID_;
  float* out_Z = out_S + (size_t)L_ * B_ * H_ * D_ * D_;

  // workspace layout (4 MB total)
  float* h = (float*)d_ws;                    // B*HID f32
  u16* hb = (u16*)(h + B_ * HID_);            // B*HID bf16
  float* qkv = (float*)(hb + B_ * HID_);      // 3*B*HID f32
  u16* attnb = (u16*)(qkv + 3 * B_ * HID_);   // B*HID bf16
  float* tmp = (float*)(attnb + B_ * HID_);   // B*HID f32
  u16* ff1 = (u16*)(tmp + B_ * HID_);         // B*FF bf16

  embed_kernel<<<B_, 256, 0, stream>>>(x, pos, emb, h, hb);
  for (int l = 0; l < L_; l++) {
    gemm_qkv<<<dim3(24, 4), 256, 0, stream>>>(hb,
        Wq + (size_t)l * HID_ * HID_, Wk + (size_t)l * HID_ * HID_,
        Wv + (size_t)l * HID_ * HID_, bq + l * HID_, bk + l * HID_, bv + l * HID_,
        qkv);
    state_kernel<<<B_ * H_, 256, 0, stream>>>(
        S + (size_t)l * B_ * H_ * D_ * D_, Z + (size_t)l * B_ * H_ * D_, qkv,
        out_S + (size_t)l * B_ * H_ * D_ * D_, out_Z + (size_t)l * B_ * H_ * D_,
        attnb);
    gemm_f32out<<<dim3(8, 4), 256, 0, stream>>>(
        attnb, Wo + (size_t)l * HID_ * HID_, bo + l * HID_, tmp, HID_, HID_, 0);
    ln_kernel<<<B_, 256, 0, stream>>>(tmp, h, ln1_g + l * HID_, ln1_b + l * HID_, h, hb);
    gemm_bf16out<<<dim3(32, 4), 256, 0, stream>>>(
        hb, W1 + (size_t)l * HID_ * FF_, b1 + l * FF_, ff1, FF_, HID_, 2);
    gemm_f32out<<<dim3(8, 4), 256, 0, stream>>>(
        ff1, W2 + (size_t)l * FF_ * HID_, b2 + l * HID_, tmp, HID_, FF_, 0);
    ln_kernel<<<B_, 256, 0, stream>>>(tmp, h, ln2_g + l * HID_, ln2_b + l * HID_, h, hb);
  }
  ln_kernel<<<B_, 256, 0, stream>>>(h, nullptr, lnf_g, lnf_b, out_h, nullptr);
}

// Round 2
// 1856.969 us; speedup vs baseline: 1.0403x; 1.0403x over previous
//
#include <hip/hip_runtime.h>
#include <math.h>

#define B_ 256
#define HID_ 512
#define H_ 8
#define D_ 64
#define FF_ 2048
#define L_ 6
#define EPS_ATTN 1e-6f
#define EPS_LN 1e-5f

typedef unsigned short u16;
typedef __attribute__((ext_vector_type(8))) short short8;
typedef __attribute__((ext_vector_type(4))) float floatx4;

__device__ inline u16 f2bf(float f) {
  union { float f; unsigned u; } un; un.f = f;
  unsigned u = un.u;
  u += 0x7FFFu + ((u >> 16) & 1u);   // RNE truncate to bf16
  return (u16)(u >> 16);
}

// ---------------- embedding + sinusoidal PE ----------------
__global__ __launch_bounds__(256) void embed_kernel(
    const int* __restrict__ x, const int* __restrict__ pos,
    const float* __restrict__ emb, float* __restrict__ h, u16* __restrict__ hb) {
  int b = blockIdx.x, t = threadIdx.x;
  int tok = x[b];
  float p = (float)pos[0];
  for (int i = t; i < HID_; i += 256) {
    int pair = i >> 1;
    float freq = powf(10000.f, -(float)pair * (1.f / 256.f));
    float ang = p * freq;
    float pe = (i & 1) ? cosf(ang) : sinf(ang);
    float v = emb[(size_t)tok * HID_ + i] + pe;
    h[b * HID_ + i] = v;
    hb[b * HID_ + i] = f2bf(v);
  }
}

// -------- weight convert: fp32 [K][N] -> bf16 WT [N][K], per layer ----------
// grid: (256, 6 matrices, n_layers); 64x64 tiles via LDS transpose
__global__ __launch_bounds__(256) void wconvert(
    const float* __restrict__ Wq, const float* __restrict__ Wk,
    const float* __restrict__ Wv, const float* __restrict__ Wo,
    const float* __restrict__ W1, const float* __restrict__ W2,
    u16* __restrict__ wt, int l0, size_t wt_stride) {
  int l = l0 + blockIdx.z;
  u16* dst = wt + (size_t)blockIdx.z * wt_stride;
  int mat = blockIdx.y;
  const float* src;
  int K, N;
  size_t doff;
  switch (mat) {
    case 0: src = Wq + (size_t)l * 262144; K = 512; N = 512; doff = 0; break;
    case 1: src = Wk + (size_t)l * 262144; K = 512; N = 512; doff = 262144; break;
    case 2: src = Wv + (size_t)l * 262144; K = 512; N = 512; doff = 524288; break;
    case 3: src = Wo + (size_t)l * 262144; K = 512; N = 512; doff = 786432; break;
    case 4: src = W1 + (size_t)l * 1048576; K = 512; N = 2048; doff = 1048576; break;
    default: src = W2 + (size_t)l * 1048576; K = 2048; N = 512; doff = 2097152; break;
  }
  int ntn = N >> 6;
  int ntiles = (K >> 6) * ntn;
  if (blockIdx.x >= ntiles) return;
  int tk = blockIdx.x / ntn, tn = blockIdx.x % ntn;
  __shared__ u16 sT[64][80];  // [n][k], pad 80 (160B rows, 16B-aligned)
  int t = threadIdx.x;
  int r = t >> 2, c = t & 3;
  const float* sp = src + (size_t)(tk * 64 + r) * N + tn * 64 + c * 16;
#pragma unroll
  for (int i = 0; i < 4; i++) {
    float4 v = *(const float4*)(sp + i * 4);
    int cb = c * 16 + i * 4;
    sT[cb + 0][r] = f2bf(v.x);
    sT[cb + 1][r] = f2bf(v.y);
    sT[cb + 2][r] = f2bf(v.z);
    sT[cb + 3][r] = f2bf(v.w);
  }
  __syncthreads();
  u16* dp = dst + doff + (size_t)(tn * 64 + r) * K + tk * 64 + c * 16;
  *(float4*)dp = *(const float4*)&sT[r][c * 16];
  *(float4*)(dp + 8) = *(const float4*)&sT[r][c * 16 + 8];
}

// ---------------- split-K bf16 MFMA GEMM ------------------------------------
// A bf16 [256][K], WT bf16 [N][K]. grid (N/64, 4, KS). BK=32, 4 waves.
// Each block writes a 64x64 fp32 partial (agent-scope stores); the last
// block per tile (counter semaphore) reduces KS partials + epilogue.
// mode 0: QKV (N=1536 logical, remap to qkv[3][256][512], elu+1 on q,k)
// mode 1: f32 out + bias
// mode 2: bf16 out + bias + relu
__global__ __launch_bounds__(256) void gemm_sk(
    const u16* __restrict__ A, const u16* __restrict__ WT,
    const float* __restrict__ b0, const float* __restrict__ b1,
    const float* __restrict__ b2, float* __restrict__ P,
    int* __restrict__ counter, float* __restrict__ outf, u16* __restrict__ outb,
    int N, int K, int KB, int mode) {
  int t = threadIdx.x;
  int lane = t & 63, wv = t >> 6;
  int m0 = blockIdx.y * 64, n0 = blockIdx.x * 64;
  int KS = gridDim.z, ks = blockIdx.z;
  int kb = ks * KB;
  int NIT = KB / 32;
  __shared__ u16 sA[64][40], sB[64][40];
  floatx4 acc[4] = {};
  const int r = t >> 2, c = t & 3;
  const u16* ap = A + (size_t)(m0 + r) * K + kb + c * 8;
  const u16* bp = WT + (size_t)(n0 + r) * K + kb + c * 8;
  float4 pa = *(const float4*)ap;
  float4 pb = *(const float4*)bp;
  for (int it = 0; it < NIT; ++it) {
    *(float4*)&sA[r][c * 8] = pa;
    *(float4*)&sB[r][c * 8] = pb;
    __syncthreads();
    if (it + 1 < NIT) {
      pa = *(const float4*)(ap + (it + 1) * 32);
      pb = *(const float4*)(bp + (it + 1) * 32);
    }
    short8 af = *(const short8*)&sA[wv * 16 + (lane & 15)][(lane >> 4) * 8];
#pragma unroll
    for (int nt = 0; nt < 4; nt++) {
      short8 bf = *(const short8*)&sB[nt * 16 + (lane & 15)][(lane >> 4) * 8];
      acc[nt] = __builtin_amdgcn_mfma_f32_16x16x32_bf16(af, bf, acc[nt], 0, 0, 0);
    }
    __syncthreads();
  }
  int tile = blockIdx.y * gridDim.x + blockIdx.x;
  float* myP = P + ((size_t)tile * KS + ks) * 4096;
#pragma unroll
  for (int nt = 0; nt < 4; nt++)
#pragma unroll
    for (int rr = 0; rr < 4; rr++) {
      int row = wv * 16 + (lane >> 4) * 4 + rr;
      int col = nt * 16 + (lane & 15);
      __hip_atomic_store(&myP[row * 64 + col], acc[nt][rr], __ATOMIC_RELAXED,
                         __HIP_MEMORY_SCOPE_AGENT);
    }
  __threadfence();
  __syncthreads();
  __shared__ int win;
  if (t == 0) {
    int old = __hip_atomic_fetch_add(counter + tile, 1, __ATOMIC_ACQ_REL,
                                     __HIP_MEMORY_SCOPE_AGENT);
    win = (old == KS - 1);
  }
  __syncthreads();
  if (!win) return;
  const float* Pt = P + (size_t)tile * KS * 4096;
#pragma unroll
  for (int i = 0; i < 16; i++) {
    int e = t + i * 256;
    float s = 0.f;
    for (int k2 = 0; k2 < KS; k2++)
      s += __hip_atomic_load(Pt + k2 * 4096 + e, __ATOMIC_RELAXED,
                             __HIP_MEMORY_SCOPE_AGENT);
    int row = m0 + (e >> 6), col = n0 + (e & 63);
    if (mode == 0) {
      int sel = col >> 9, cc = col & 511;
      s += (sel == 0 ? b0 : sel == 1 ? b1 : b2)[cc];
      if (sel < 2) s = s > 0.f ? s + 1.f : expf(s);
      outf[(size_t)sel * (B_ * HID_) + (size_t)row * HID_ + cc] = s;
    } else if (mode == 1) {
      s += b0[col];
      outf[(size_t)row * N + col] = s;
    } else {
      s += b0[col];
      s = fmaxf(s, 0.f);
      outb[(size_t)row * N + col] = f2bf(s);
    }
  }
}

// ---------------- linear-attention state update (HBM-bound) -----------------
__global__ __launch_bounds__(256) void state_kernel(
    const float* __restrict__ S_in, const float* __restrict__ Z_in,
    const float* __restrict__ qkv, float* __restrict__ S_out,
    float* __restrict__ Z_out, u16* __restrict__ attnb) {
  int bh = blockIdx.x;
  int b = bh >> 3, hh = bh & 7;
  const float* q = qkv + (size_t)b * HID_ + hh * D_;
  const float* k = q + (size_t)B_ * HID_;
  const float* v = q + (size_t)2 * B_ * HID_;
  __shared__ float qs[D_], ks[D_], vs[D_];
  __shared__ float part[16][D_];
  int t = threadIdx.x;
  if (t < D_) { qs[t] = q[t]; ks[t] = k[t]; vs[t] = v[t]; }
  __syncthreads();
  int tm = (t & 15) << 2;
  int rg = t >> 4;
  const float4* Sp = (const float4*)(S_in + (size_t)bh * D_ * D_);
  float4* So = (float4*)(S_out + (size_t)bh * D_ * D_);
  float4 vv = *(const float4*)(vs + tm);
  float4 acc = {0.f, 0.f, 0.f, 0.f};
#pragma unroll
  for (int i = 0; i < 4; i++) {
    int d = rg * 4 + i;
    float kd = ks[d], qd = qs[d];
    float4 s = Sp[(d * D_ + tm) >> 2];
    s.x += kd * vv.x; s.y += kd * vv.y; s.z += kd * vv.z; s.w += kd * vv.w;
    So[(d * D_ + tm) >> 2] = s;
    acc.x += qd * s.x; acc.y += qd * s.y; acc.z += qd * s.z; acc.w += qd * s.w;
  }
  *(float4*)(&part[rg][tm]) = acc;
  __syncthreads();
  if (t < D_) {
    float num = 0.f;
#pragma unroll
    for (int r = 0; r < 16; r++) num += part[r][t];
    float zk = Z_in[(size_t)bh * D_ + t] + ks[t];
    Z_out[(size_t)bh * D_ + t] = zk;
    float dv = qs[t] * zk;
#pragma unroll
    for (int off = 32; off > 0; off >>= 1) dv += __shfl_down(dv, off);
    float den = __shfl(dv, 0) + EPS_ATTN;
    attnb[(size_t)b * HID_ + hh * D_ + t] = f2bf(num / den);
  }
}

// ---------------- residual + LayerNorm --------------------------------------
__global__ __launch_bounds__(256) void ln_kernel(
    const float* __restrict__ x, const float* __restrict__ res,
    const float* __restrict__ g, const float* __restrict__ bb,
    float* __restrict__ out_f, u16* __restrict__ out_b) {
  int b = blockIdx.x, t = threadIdx.x;
  float v0 = x[b * HID_ + t] + (res ? res[b * HID_ + t] : 0.f);
  float v1 = x[b * HID_ + 256 + t] + (res ? res[b * HID_ + 256 + t] : 0.f);
  float s = v0 + v1, ss = v0 * v0 + v1 * v1;
#pragma unroll
  for (int off = 32; off > 0; off >>= 1) {
    s += __shfl_down(s, off);
    ss += __shfl_down(ss, off);
  }
  __shared__ float rs[4], rss[4];
  int w = t >> 6;
  if ((t & 63) == 0) { rs[w] = s; rss[w] = ss; }
  __syncthreads();
  float S = rs[0] + rs[1] + rs[2] + rs[3];
  float SS = rss[0] + rss[1] + rss[2] + rss[3];
  float mean = S * (1.f / HID_);
  float var = SS * (1.f / HID_) - mean * mean;
  float inv = rsqrtf(var + EPS_LN);
  float o0 = (v0 - mean) * inv * g[t] + bb[t];
  float o1 = (v1 - mean) * inv * g[256 + t] + bb[256 + t];
  out_f[b * HID_ + t] = o0;
  out_f[b * HID_ + 256 + t] = o1;
  if (out_b) {
    out_b[b * HID_ + t] = f2bf(o0);
    out_b[b * HID_ + 256 + t] = f2bf(o1);
  }
}

extern "C" void kernel_launch(void* const* d_in, const int* in_sizes, int n_in,
                              void* d_out, int out_size, void* d_ws, size_t ws_size,
                              hipStream_t stream) {
  const int* x = (const int*)d_in[0];
  const int* pos = (const int*)d_in[1];
  const float* S = (const float*)d_in[2];
  const float* Z = (const float*)d_in[3];
  const float* emb = (const float*)d_in[4];
  const float* Wq = (const float*)d_in[5];
  const float* bq = (const float*)d_in[6];
  const float* Wk = (const float*)d_in[7];
  const float* bk = (const float*)d_in[8];
  const float* Wv = (const float*)d_in[9];
  const float* bv = (const float*)d_in[10];
  const float* Wo = (const float*)d_in[11];
  const float* bo = (const float*)d_in[12];
  const float* W1 = (const float*)d_in[13];
  const float* b1 = (const float*)d_in[14];
  const float* W2 = (const float*)d_in[15];
  const float* b2 = (const float*)d_in[16];
  const float* ln1_g = (const float*)d_in[17];
  const float* ln1_b = (const float*)d_in[18];
  const float* ln2_g = (const float*)d_in[19];
  const float* ln2_b = (const float*)d_in[20];
  const float* lnf_g = (const float*)d_in[21];
  const float* lnf_b = (const float*)d_in[22];

  float* out_h = (float*)d_out;
  float* out_S = out_h + (size_t)B_ * HID_;
  float* out_Z = out_S + (size_t)L_ * B_ * H_ * D_ * D_;

  // ---- workspace layout (byte offsets) ----
  char* w = (char*)d_ws;
  float* h     = (float*)(w + 0);          // 512 KB
  u16*   hb    = (u16*)(w + 524288);       // 256 KB
  u16*   attnb = (u16*)(w + 786432);       // 256 KB
  u16*   ff1   = (u16*)(w + 1048576);      // 1 MB
  float* qkv   = (float*)(w + 2097152);    // 1.5 MB
  float* tmpA  = (float*)(w + 3670016);    // 512 KB
  float* tmpB  = (float*)(w + 4194304);    // 512 KB
  int*   cnt   = (int*)(w + 4718592);      // 2 KB
  float* P     = (float*)(w + 4720640);    // 8 MB partials
  u16*   wt    = (u16*)(w + 13109248);     // 6.29 MB/layer
  const size_t WT_LAYER = 3145728;         // u16 elements per layer
  bool bigws = ws_size >= (size_t)13109248 + WT_LAYER * 2 * L_;

  embed_kernel<<<B_, 256, 0, stream>>>(x, pos, emb, h, hb);
  if (bigws)
    wconvert<<<dim3(256, 6, L_), 256, 0, stream>>>(Wq, Wk, Wv, Wo, W1, W2,
                                                   wt, 0, WT_LAYER);
  for (int l = 0; l < L_; l++) {
    u16* wtl = bigws ? wt + (size_t)l * WT_LAYER : wt;
    hipMemsetAsync(cnt, 0, 2048, stream);
    if (!bigws)
      wconvert<<<dim3(256, 6, 1), 256, 0, stream>>>(Wq, Wk, Wv, Wo, W1, W2,
                                                    wtl, l, 0);
    // QKV: N=1536 logical, K=512, KS=4 (384 blocks)
    gemm_sk<<<dim3(24, 4, 4), 256, 0, stream>>>(
        hb, wtl, bq + l * HID_, bk + l * HID_, bv + l * HID_,
        P, cnt + 0, qkv, nullptr, 1536, 512, 128, 0);
    state_kernel<<<B_ * H_, 256, 0, stream>>>(
        S + (size_t)l * B_ * H_ * D_ * D_, Z + (size_t)l * B_ * H_ * D_, qkv,
        out_S + (size_t)l * B_ * H_ * D_ * D_, out_Z + (size_t)l * B_ * H_ * D_,
        attnb);
    // Wo: N=512, K=512, KS=8 (256 blocks)
    gemm_sk<<<dim3(8, 4, 8), 256, 0, stream>>>(
        attnb, wtl + 786432, bo + l * HID_, nullptr, nullptr,
        P, cnt + 96, tmpA, nullptr, 512, 512, 64, 1);
    ln_kernel<<<B_, 256, 0, stream>>>(tmpA, h, ln1_g + l * HID_, ln1_b + l * HID_, h, hb);
    // W1: N=2048, K=512, KS=4 (512 blocks)
    gemm_sk<<<dim3(32, 4, 4), 256, 0, stream>>>(
        hb, wtl + 1048576, b1 + l * FF_, nullptr, nullptr,
        P, cnt + 128, nullptr, ff1, 2048, 512, 128, 2);
    // W2: N=512, K=2048, KS=8 (256 blocks)
    gemm_sk<<<dim3(8, 4, 8), 256, 0, stream>>>(
        ff1, wtl + 2097152, b2 + l * HID_, nullptr, nullptr,
        P, cnt + 256, tmpB, nullptr, 512, 2048, 256, 1);
    ln_kernel<<<B_, 256, 0, stream>>>(tmpB, h, ln2_g + l * HID_, ln2_b + l * HID_, h, hb);
  }
  ln_kernel<<<B_, 256, 0, stream>>>(h, nullptr, lnf_g, lnf_b, out_h, nullptr);
}